// Round 7
// baseline (283.915 us; speedup 1.0000x reference)
//
#include <hip/hip_runtime.h>
#include <hip/hip_bf16.h>
#include <stdint.h>

typedef __bf16 bf16x8 __attribute__((ext_vector_type(8)));
typedef float  f32x4  __attribute__((ext_vector_type(4)));

__device__ __forceinline__ int imin(int a, int b) { return a < b ? a : b; }
__device__ __forceinline__ int imax(int a, int b) { return a > b ? a : b; }

#define TMASK ((1u << 19) - 1u)

__constant__ int cRES[16] = {16, 23, 31, 43, 59, 81, 112, 154,
                             213, 295, 407, 562, 777, 1073, 1483, 2048};

// ---------------- Kernel A: hash-grid encode, 4 points/thread ----------------
// Single launch, level = bid & 15. Block covers 1024 consecutive points of one
// level; thread q-th point = pblk + q*256 (coalesced). 32 independent gathers
// in flight per thread to saturate the CU address unit (TA) — encode is
// gather-issue-bound, not fetch-bound (round-6: L2-resident and thrashing
// levels both ran 61 us). xin via NT loads, enc via NT stores: keep L2 for table.
__global__ void __launch_bounds__(256) ngp_encode4(
    const float* __restrict__ xin,
    const float2* __restrict__ tab,
    float2* __restrict__ enc,
    int n)
{
    const int bid = blockIdx.x;
    const int l = bid & 15;
    const int pblk = (bid >> 4) * 1024 + threadIdx.x;

    const int rm = cRES[l] - 1;
    const float rf = (float)rm;
    const uint32_t base = (uint32_t)l << 19;

    uint32_t idx[4][8];
    float wa[4][3];

    #pragma unroll
    for (int q = 0; q < 4; ++q) {
        const int p = pblk + q * 256;
        const float x0 = __builtin_nontemporal_load(&xin[3 * p + 0]);
        const float x1 = __builtin_nontemporal_load(&xin[3 * p + 1]);
        const float x2 = __builtin_nontemporal_load(&xin[3 * p + 2]);
        const float xn0 = (x0 + 1.0f) * 0.5f;
        const float xn1 = (x1 + 1.0f) * 0.5f;
        const float xn2 = (x2 + 1.0f) * 0.5f;

        const float p0 = xn0 * rf, p1 = xn1 * rf, p2 = xn2 * rf;
        const float f0 = floorf(p0), f1 = floorf(p1), f2 = floorf(p2);
        const int i0 = (int)f0, i1 = (int)f1, i2 = (int)f2;
        wa[q][0] = p0 - f0; wa[q][1] = p1 - f1; wa[q][2] = p2 - f2;

        const int a0 = imax(imin(i0, rm), 0), b0 = imax(imin(i0 + 1, rm), 0);
        const int a1 = imax(imin(i1, rm), 0), b1 = imax(imin(i1 + 1, rm), 0);
        const int a2 = imax(imin(i2, rm), 0), b2 = imax(imin(i2 + 1, rm), 0);

        const uint32_t t0a = (uint32_t)a0;
        const uint32_t t0b = (uint32_t)b0;
        const uint32_t t1a = (uint32_t)a1 * 2654435761u;
        const uint32_t t1b = (uint32_t)b1 * 2654435761u;
        const uint32_t t2a = (uint32_t)a2 * 805459861u;
        const uint32_t t2b = (uint32_t)b2 * 805459861u;

        idx[q][0] = base + ((t0a ^ t1a ^ t2a) & TMASK);
        idx[q][1] = base + ((t0b ^ t1a ^ t2a) & TMASK);
        idx[q][2] = base + ((t0a ^ t1b ^ t2a) & TMASK);
        idx[q][3] = base + ((t0b ^ t1b ^ t2a) & TMASK);
        idx[q][4] = base + ((t0a ^ t1a ^ t2b) & TMASK);
        idx[q][5] = base + ((t0b ^ t1a ^ t2b) & TMASK);
        idx[q][6] = base + ((t0a ^ t1b ^ t2b) & TMASK);
        idx[q][7] = base + ((t0b ^ t1b ^ t2b) & TMASK);
    }

    // batch all 32 gathers (independent -> deep vmcnt pipeline)
    float2 v[4][8];
    #pragma unroll
    for (int q = 0; q < 4; ++q)
        #pragma unroll
        for (int cor = 0; cor < 8; ++cor)
            v[q][cor] = tab[idx[q][cor]];

    #pragma unroll
    for (int q = 0; q < 4; ++q) {
        const float w0 = wa[q][0], w1 = wa[q][1], w2 = wa[q][2];
        const float u0 = 1.0f - w0, u1 = 1.0f - w1, u2 = 1.0f - w2;
        float e0 = 0.0f, e1 = 0.0f;
        {   float cw = u0 * u1 * u2;  e0 = fmaf(v[q][0].x, cw, e0); e1 = fmaf(v[q][0].y, cw, e1); }
        {   float cw = w0 * u1 * u2;  e0 = fmaf(v[q][1].x, cw, e0); e1 = fmaf(v[q][1].y, cw, e1); }
        {   float cw = u0 * w1 * u2;  e0 = fmaf(v[q][2].x, cw, e0); e1 = fmaf(v[q][2].y, cw, e1); }
        {   float cw = w0 * w1 * u2;  e0 = fmaf(v[q][3].x, cw, e0); e1 = fmaf(v[q][3].y, cw, e1); }
        {   float cw = u0 * u1 * w2;  e0 = fmaf(v[q][4].x, cw, e0); e1 = fmaf(v[q][4].y, cw, e1); }
        {   float cw = w0 * u1 * w2;  e0 = fmaf(v[q][5].x, cw, e0); e1 = fmaf(v[q][5].y, cw, e1); }
        {   float cw = u0 * w1 * w2;  e0 = fmaf(v[q][6].x, cw, e0); e1 = fmaf(v[q][6].y, cw, e1); }
        {   float cw = w0 * w1 * w2;  e0 = fmaf(v[q][7].x, cw, e0); e1 = fmaf(v[q][7].y, cw, e1); }

        union { double d; float2 f; } u;
        u.f = make_float2(e0, e1);
        const int p = pblk + q * 256;
        __builtin_nontemporal_store(u.d, (double*)&enc[(size_t)l * n + p]);
    }
}

// ---------------- Kernel B: MFMA MLP ----------------
// Wave = 16 points. 20x mfma_f32_16x16x32_bf16 per tile.
// Fragment layouts (gfx950):
//   A[row][k]: row = lane&15, k = 8*(lane>>4)+j
//   B[k][col]: col = lane&15, k = 8*(lane>>4)+j
//   D[row][col]: col = lane&15, row = 4*(lane>>4)+reg
// Inter-layer transpose via per-wave LDS tile [16][68].
__global__ void __launch_bounds__(256) ngp_mlp_mfma(
    const float2* __restrict__ enc,   // [16][N]
    const float* __restrict__ din,
    const float* __restrict__ W1,     // [32][64]
    const float* __restrict__ W2,     // [64][16]
    const float* __restrict__ WIN,    // [32][64]
    const float* __restrict__ WH,     // [64][64]
    const float* __restrict__ WOUT,   // [64][3]
    float* __restrict__ out,
    int n, int ntiles)
{
    __shared__ float lds[4][16 * 68];
    const int tid  = threadIdx.x;
    const int wid  = tid >> 6;
    const int lane = tid & 63;
    const int c = lane & 15;   // A-row (point) / B-col / D-col
    const int g = lane >> 4;   // k-group
    float* buf = &lds[wid][0];

    // ---- load weight fragments once (held in VGPRs across the tile loop) ----
    bf16x8 w1f[4], w2f[2], winf[4], whf[2][4], woutf[2];
    #pragma unroll
    for (int n4 = 0; n4 < 4; ++n4)
        #pragma unroll
        for (int j = 0; j < 8; ++j)
            w1f[n4][j] = (__bf16)W1[(g * 8 + j) * 64 + n4 * 16 + c];
    #pragma unroll
    for (int kc = 0; kc < 2; ++kc)
        #pragma unroll
        for (int j = 0; j < 8; ++j)
            w2f[kc][j] = (__bf16)W2[(kc * 32 + g * 8 + j) * 16 + c];
    #pragma unroll
    for (int n4 = 0; n4 < 4; ++n4)
        #pragma unroll
        for (int j = 0; j < 8; ++j)
            winf[n4][j] = (__bf16)WIN[(g * 8 + j) * 64 + n4 * 16 + c];
    #pragma unroll
    for (int kc = 0; kc < 2; ++kc)
        #pragma unroll
        for (int n4 = 0; n4 < 4; ++n4)
            #pragma unroll
            for (int j = 0; j < 8; ++j)
                whf[kc][n4][j] = (__bf16)WH[(kc * 32 + g * 8 + j) * 64 + n4 * 16 + c];
    #pragma unroll
    for (int kc = 0; kc < 2; ++kc)
        #pragma unroll
        for (int j = 0; j < 8; ++j)
            woutf[kc][j] = (c < 3) ? (__bf16)WOUT[(kc * 32 + g * 8 + j) * 3 + c]
                                   : (__bf16)0.0f;

    for (int t = blockIdx.x; t < ntiles; t += gridDim.x) {
        const int pbase = t * 64 + wid * 16;
        const int pc = pbase + c;

        // ---- A1 from enc: feats k=8g..8g+7 = levels 4g..4g+3 x {x,y} ----
        bf16x8 a1;
        #pragma unroll
        for (int m = 0; m < 4; ++m) {
            const float2 e = enc[(size_t)(4 * g + m) * n + pc];
            a1[2 * m]     = (__bf16)e.x;
            a1[2 * m + 1] = (__bf16)e.y;
        }

        // ---- layer 1: D1 = A1 @ W1 ; relu -> LDS [16pt][64f] ----
        #pragma unroll
        for (int n4 = 0; n4 < 4; ++n4) {
            f32x4 d = {0.f, 0.f, 0.f, 0.f};
            d = __builtin_amdgcn_mfma_f32_16x16x32_bf16(a1, w1f[n4], d, 0, 0, 0);
            #pragma unroll
            for (int r = 0; r < 4; ++r)
                buf[(g * 4 + r) * 68 + n4 * 16 + c] = fmaxf(d[r], 0.0f);
        }

        // ---- layer 2: h = relu(h1) @ W2 (K=64 -> 2 chunks, N=16) ----
        f32x4 hacc = {0.f, 0.f, 0.f, 0.f};
        #pragma unroll
        for (int kc = 0; kc < 2; ++kc) {
            bf16x8 a2;
            const float* src = &buf[c * 68 + kc * 32 + g * 8];
            #pragma unroll
            for (int j = 0; j < 8; ++j) a2[j] = (__bf16)src[j];
            hacc = __builtin_amdgcn_mfma_f32_16x16x32_bf16(a2, w2f[kc], hacc, 0, 0, 0);
        }

        // sigma = exp(h[:,0])
        if (c == 0) {
            #pragma unroll
            for (int r = 0; r < 4; ++r)
                out[pbase + g * 4 + r] = __expf(hacc[r]);
        }

        // stage raw h into LDS cols 0..15
        #pragma unroll
        for (int r = 0; r < 4; ++r)
            buf[(g * 4 + r) * 68 + c] = hacc[r];

        // ---- SH degree 4 for point pc ----
        const float dx = din[3 * pc + 0];
        const float dy = din[3 * pc + 1];
        const float dz = din[3 * pc + 2];
        const float xy = dx * dy, xz = dx * dz, yz = dy * dz;
        const float x2 = dx * dx, y2 = dy * dy, z2 = dz * dz;
        float shv[16];
        shv[0]  = 0.28209479177387814f;
        shv[1]  = -0.48860251190291987f * dy;
        shv[2]  = 0.48860251190291987f * dz;
        shv[3]  = -0.48860251190291987f * dx;
        shv[4]  = 1.0925484305920792f * xy;
        shv[5]  = -1.0925484305920792f * yz;
        shv[6]  = 0.94617469575756f * z2 - 0.31539156525252f;
        shv[7]  = -1.0925484305920792f * xz;
        shv[8]  = 0.5462742152960396f * (x2 - y2);
        shv[9]  = 0.5900435899266435f * dy * (-3.0f * x2 + y2);
        shv[10] = 2.890611442640554f * xy * dz;
        shv[11] = 0.4570457994644657f * dy * (1.0f - 5.0f * z2);
        shv[12] = 0.3731763325901154f * dz * (5.0f * z2 - 3.0f);
        shv[13] = 0.4570457994644657f * dx * (1.0f - 5.0f * z2);
        shv[14] = 1.445305721320277f * dz * (x2 - y2);
        shv[15] = 0.5900435899266435f * dx * (-x2 + 3.0f * y2);

        // ---- A3 = concat([sh, h]) : k 0..15 sh, 16..31 h ----
        bf16x8 a3;
        if (g < 2) {
            #pragma unroll
            for (int j = 0; j < 8; ++j) a3[j] = (__bf16)shv[g * 8 + j];
        } else {
            const float* hsrc = &buf[c * 68 + (g - 2) * 8];
            #pragma unroll
            for (int j = 0; j < 8; ++j) a3[j] = (__bf16)hsrc[j];
        }

        // ---- layer 3: D3 = A3 @ WIN ; relu -> LDS ----
        #pragma unroll
        for (int n4 = 0; n4 < 4; ++n4) {
            f32x4 d = {0.f, 0.f, 0.f, 0.f};
            d = __builtin_amdgcn_mfma_f32_16x16x32_bf16(a3, winf[n4], d, 0, 0, 0);
            #pragma unroll
            for (int r = 0; r < 4; ++r)
                buf[(g * 4 + r) * 68 + n4 * 16 + c] = fmaxf(d[r], 0.0f);
        }

        // ---- layer 4: D4 = A4 @ WH ; relu -> LDS ----
        bf16x8 a4[2];
        #pragma unroll
        for (int kc = 0; kc < 2; ++kc) {
            const float* src = &buf[c * 68 + kc * 32 + g * 8];
            #pragma unroll
            for (int j = 0; j < 8; ++j) a4[kc][j] = (__bf16)src[j];
        }
        f32x4 d4[4];
        #pragma unroll
        for (int n4 = 0; n4 < 4; ++n4) d4[n4] = (f32x4){0.f, 0.f, 0.f, 0.f};
        #pragma unroll
        for (int kc = 0; kc < 2; ++kc)
            #pragma unroll
            for (int n4 = 0; n4 < 4; ++n4)
                d4[n4] = __builtin_amdgcn_mfma_f32_16x16x32_bf16(a4[kc], whf[kc][n4], d4[n4], 0, 0, 0);
        #pragma unroll
        for (int n4 = 0; n4 < 4; ++n4)
            #pragma unroll
            for (int r = 0; r < 4; ++r)
                buf[(g * 4 + r) * 68 + n4 * 16 + c] = fmaxf(d4[n4][r], 0.0f);

        // ---- layer 5: D5 = A5 @ WOUT(pad16) ; sigmoid ; store rgb ----
        f32x4 d5 = {0.f, 0.f, 0.f, 0.f};
        #pragma unroll
        for (int kc = 0; kc < 2; ++kc) {
            bf16x8 a5;
            const float* src = &buf[c * 68 + kc * 32 + g * 8];
            #pragma unroll
            for (int j = 0; j < 8; ++j) a5[j] = (__bf16)src[j];
            d5 = __builtin_amdgcn_mfma_f32_16x16x32_bf16(a5, woutf[kc], d5, 0, 0, 0);
        }
        if (c < 3) {
            #pragma unroll
            for (int r = 0; r < 4; ++r)
                out[n + 3 * (pbase + g * 4 + r) + c] = 1.0f / (1.0f + __expf(-d5[r]));
        }
    }
}

// ---------------- Fallback scalar MLP ----------------
__global__ void __launch_bounds__(256) ngp_mlp(
    const float2* __restrict__ enc, const float* __restrict__ din,
    const float* __restrict__ W1, const float* __restrict__ W2,
    const float* __restrict__ WIN, const float* __restrict__ WH,
    const float* __restrict__ WOUT, float* __restrict__ out, int n)
{
    const int i = blockIdx.x * 256 + threadIdx.x;
    if (i >= n) return;
    float h1[64];
    #pragma unroll
    for (int j = 0; j < 64; ++j) h1[j] = 0.0f;
    #pragma unroll
    for (int l = 0; l < 16; ++l) {
        const float2 e = enc[(size_t)l * n + i];
        #pragma unroll
        for (int j = 0; j < 64; ++j)
            h1[j] = fmaf(e.x, W1[(2 * l) * 64 + j], fmaf(e.y, W1[(2 * l + 1) * 64 + j], h1[j]));
    }
    float h[16];
    #pragma unroll
    for (int j = 0; j < 16; ++j) h[j] = 0.0f;
    #pragma unroll
    for (int k = 0; k < 64; ++k) {
        const float v = fmaxf(h1[k], 0.0f);
        #pragma unroll
        for (int j = 0; j < 16; ++j) h[j] = fmaf(v, W2[k * 16 + j], h[j]);
    }
    out[i] = __expf(h[0]);
    const float dx = din[3 * i + 0], dy = din[3 * i + 1], dz = din[3 * i + 2];
    const float xy = dx * dy, xz = dx * dz, yz = dy * dz;
    const float x2 = dx * dx, y2 = dy * dy, z2 = dz * dz;
    float sh[16];
    sh[0]  = 0.28209479177387814f;
    sh[1]  = -0.48860251190291987f * dy;
    sh[2]  = 0.48860251190291987f * dz;
    sh[3]  = -0.48860251190291987f * dx;
    sh[4]  = 1.0925484305920792f * xy;
    sh[5]  = -1.0925484305920792f * yz;
    sh[6]  = 0.94617469575756f * z2 - 0.31539156525252f;
    sh[7]  = -1.0925484305920792f * xz;
    sh[8]  = 0.5462742152960396f * (x2 - y2);
    sh[9]  = 0.5900435899266435f * dy * (-3.0f * x2 + y2);
    sh[10] = 2.890611442640554f * xy * dz;
    sh[11] = 0.4570457994644657f * dy * (1.0f - 5.0f * z2);
    sh[12] = 0.3731763325901154f * dz * (5.0f * z2 - 3.0f);
    sh[13] = 0.4570457994644657f * dx * (1.0f - 5.0f * z2);
    sh[14] = 1.445305721320277f * dz * (x2 - y2);
    sh[15] = 0.5900435899266435f * dx * (-x2 + 3.0f * y2);
    float av[64];
    #pragma unroll
    for (int j = 0; j < 64; ++j) av[j] = 0.0f;
    #pragma unroll
    for (int k = 0; k < 16; ++k) {
        const float v = sh[k];
        #pragma unroll
        for (int j = 0; j < 64; ++j) av[j] = fmaf(v, WIN[k * 64 + j], av[j]);
    }
    #pragma unroll
    for (int k = 0; k < 16; ++k) {
        const float v = h[k];
        #pragma unroll
        for (int j = 0; j < 64; ++j) av[j] = fmaf(v, WIN[(16 + k) * 64 + j], av[j]);
    }
    float bv[64];
    #pragma unroll
    for (int j = 0; j < 64; ++j) bv[j] = 0.0f;
    #pragma unroll
    for (int k = 0; k < 64; ++k) {
        const float v = fmaxf(av[k], 0.0f);
        #pragma unroll
        for (int j = 0; j < 64; ++j) bv[j] = fmaf(v, WH[k * 64 + j], bv[j]);
    }
    float r0 = 0.0f, r1 = 0.0f, r2 = 0.0f;
    #pragma unroll
    for (int k = 0; k < 64; ++k) {
        const float v = fmaxf(bv[k], 0.0f);
        r0 = fmaf(v, WOUT[k * 3 + 0], r0);
        r1 = fmaf(v, WOUT[k * 3 + 1], r1);
        r2 = fmaf(v, WOUT[k * 3 + 2], r2);
    }
    out[n + 3 * i + 0] = 1.0f / (1.0f + __expf(-r0));
    out[n + 3 * i + 1] = 1.0f / (1.0f + __expf(-r1));
    out[n + 3 * i + 2] = 1.0f / (1.0f + __expf(-r2));
}

extern "C" void kernel_launch(void* const* d_in, const int* in_sizes, int n_in,
                              void* d_out, int out_size, void* d_ws, size_t ws_size,
                              hipStream_t stream)
{
    const float* x    = (const float*)d_in[0];
    const float* d    = (const float*)d_in[1];
    const float* tb   = (const float*)d_in[2];
    const float* w1   = (const float*)d_in[3];
    const float* w2   = (const float*)d_in[4];
    const float* win  = (const float*)d_in[5];
    const float* wh   = (const float*)d_in[6];
    const float* wout = (const float*)d_in[7];

    const int n = in_sizes[0] / 3;   // 262144
    const size_t enc_bytes = (size_t)16 * n * sizeof(float2);  // 33.5 MB
    float2* enc = (float2*)d_ws;

    // encode: single launch, 4 points/thread, level = bid & 15
    ngp_encode4<<<(n / 1024) * 16, 256, 0, stream>>>(x, (const float2*)tb, enc, n);

    if (ws_size >= enc_bytes) {
        const int ntiles = n / 64;   // 4096
        ngp_mlp_mfma<<<1024, 256, 0, stream>>>(enc, d, w1, w2, win, wh, wout,
                                               (float*)d_out, n, ntiles);
    } else {
        ngp_mlp<<<n / 256, 256, 0, stream>>>(enc, d, w1, w2, win, wh, wout,
                                             (float*)d_out, n);
    }
}

// Round 8
// 231.984 us; speedup vs baseline: 1.2239x; 1.2239x over previous
//
#include <hip/hip_runtime.h>
#include <hip/hip_bf16.h>
#include <stdint.h>

typedef __bf16 bf16x8 __attribute__((ext_vector_type(8)));
typedef float  f32x4  __attribute__((ext_vector_type(4)));

__device__ __forceinline__ int imin(int a, int b) { return a < b ? a : b; }
__device__ __forceinline__ int imax(int a, int b) { return a > b ? a : b; }

#define TMASK ((1u << 19) - 1u)

__constant__ int cRES[16] = {16, 23, 31, 43, 59, 81, 112, 154,
                             213, 295, 407, 562, 777, 1073, 1483, 2048};

// ---------------- Kernel A: hash-grid encode, 2 points/thread ----------------
// Single launch, two halves: half 0 = levels 0-7, half 1 = levels 8-15.
// Within a half: l = b & 7 -> with round-robin block->XCD dispatch each XCD's
// L2 sees ONE 4 MB table window (4096 blocks/half, 4096%8==0 keeps alignment).
// 2 pts/thread = 16 independent gathers in flight; sched_barrier pins the
// batch so the compiler can't sink loads to uses (r7 failure mode).
// xin via normal cached loads; enc via NT stores (keep L2 for the table).
__global__ void __launch_bounds__(256) ngp_encode2(
    const float* __restrict__ xin,
    const float2* __restrict__ tab,
    float2* __restrict__ enc,
    int n, int nblk_half)
{
    const int bid = blockIdx.x;
    const int half = (bid >= nblk_half) ? 1 : 0;
    const int b = bid - half * nblk_half;
    const int l = (b & 7) + 8 * half;
    const int pbase = (b >> 3) * 512 + threadIdx.x;

    const int rm = cRES[l] - 1;
    const float rf = (float)rm;
    const uint32_t base = (uint32_t)l << 19;

    uint32_t idx[2][8];
    float wa[2][3];

    #pragma unroll
    for (int q = 0; q < 2; ++q) {
        const int p = pbase + q * 256;
        const float xn0 = (xin[3 * p + 0] + 1.0f) * 0.5f;
        const float xn1 = (xin[3 * p + 1] + 1.0f) * 0.5f;
        const float xn2 = (xin[3 * p + 2] + 1.0f) * 0.5f;

        const float p0 = xn0 * rf, p1 = xn1 * rf, p2 = xn2 * rf;
        const float f0 = floorf(p0), f1 = floorf(p1), f2 = floorf(p2);
        const int i0 = (int)f0, i1 = (int)f1, i2 = (int)f2;
        wa[q][0] = p0 - f0; wa[q][1] = p1 - f1; wa[q][2] = p2 - f2;

        const int a0 = imax(imin(i0, rm), 0), b0 = imax(imin(i0 + 1, rm), 0);
        const int a1 = imax(imin(i1, rm), 0), b1 = imax(imin(i1 + 1, rm), 0);
        const int a2 = imax(imin(i2, rm), 0), b2 = imax(imin(i2 + 1, rm), 0);

        const uint32_t t0a = (uint32_t)a0;
        const uint32_t t0b = (uint32_t)b0;
        const uint32_t t1a = (uint32_t)a1 * 2654435761u;
        const uint32_t t1b = (uint32_t)b1 * 2654435761u;
        const uint32_t t2a = (uint32_t)a2 * 805459861u;
        const uint32_t t2b = (uint32_t)b2 * 805459861u;

        idx[q][0] = base + ((t0a ^ t1a ^ t2a) & TMASK);
        idx[q][1] = base + ((t0b ^ t1a ^ t2a) & TMASK);
        idx[q][2] = base + ((t0a ^ t1b ^ t2a) & TMASK);
        idx[q][3] = base + ((t0b ^ t1b ^ t2a) & TMASK);
        idx[q][4] = base + ((t0a ^ t1a ^ t2b) & TMASK);
        idx[q][5] = base + ((t0b ^ t1a ^ t2b) & TMASK);
        idx[q][6] = base + ((t0a ^ t1b ^ t2b) & TMASK);
        idx[q][7] = base + ((t0b ^ t1b ^ t2b) & TMASK);
    }

    // issue all 16 gathers before any consumption
    float2 v[2][8];
    #pragma unroll
    for (int q = 0; q < 2; ++q)
        #pragma unroll
        for (int cor = 0; cor < 8; ++cor)
            v[q][cor] = tab[idx[q][cor]];

    __builtin_amdgcn_sched_barrier(0);   // keep the load batch above consumers

    #pragma unroll
    for (int q = 0; q < 2; ++q) {
        const float w0 = wa[q][0], w1 = wa[q][1], w2 = wa[q][2];
        const float u0 = 1.0f - w0, u1 = 1.0f - w1, u2 = 1.0f - w2;
        float e0 = 0.0f, e1 = 0.0f;
        {   float cw = u0 * u1 * u2;  e0 = fmaf(v[q][0].x, cw, e0); e1 = fmaf(v[q][0].y, cw, e1); }
        {   float cw = w0 * u1 * u2;  e0 = fmaf(v[q][1].x, cw, e0); e1 = fmaf(v[q][1].y, cw, e1); }
        {   float cw = u0 * w1 * u2;  e0 = fmaf(v[q][2].x, cw, e0); e1 = fmaf(v[q][2].y, cw, e1); }
        {   float cw = w0 * w1 * u2;  e0 = fmaf(v[q][3].x, cw, e0); e1 = fmaf(v[q][3].y, cw, e1); }
        {   float cw = u0 * u1 * w2;  e0 = fmaf(v[q][4].x, cw, e0); e1 = fmaf(v[q][4].y, cw, e1); }
        {   float cw = w0 * u1 * w2;  e0 = fmaf(v[q][5].x, cw, e0); e1 = fmaf(v[q][5].y, cw, e1); }
        {   float cw = u0 * w1 * w2;  e0 = fmaf(v[q][6].x, cw, e0); e1 = fmaf(v[q][6].y, cw, e1); }
        {   float cw = w0 * w1 * w2;  e0 = fmaf(v[q][7].x, cw, e0); e1 = fmaf(v[q][7].y, cw, e1); }

        union { double d; float2 f; } u;
        u.f = make_float2(e0, e1);
        const int p = pbase + q * 256;
        __builtin_nontemporal_store(u.d, (double*)&enc[(size_t)l * n + p]);
    }
}

// ---------------- Kernel B: MFMA MLP ----------------
// Wave = 16 points. 20x mfma_f32_16x16x32_bf16 per tile.
// Fragment layouts (gfx950):
//   A[row][k]: row = lane&15, k = 8*(lane>>4)+j
//   B[k][col]: col = lane&15, k = 8*(lane>>4)+j
//   D[row][col]: col = lane&15, row = 4*(lane>>4)+reg
// Inter-layer transpose via per-wave LDS tile [16][68].
__global__ void __launch_bounds__(256) ngp_mlp_mfma(
    const float2* __restrict__ enc,   // [16][N]
    const float* __restrict__ din,
    const float* __restrict__ W1,     // [32][64]
    const float* __restrict__ W2,     // [64][16]
    const float* __restrict__ WIN,    // [32][64]
    const float* __restrict__ WH,     // [64][64]
    const float* __restrict__ WOUT,   // [64][3]
    float* __restrict__ out,
    int n, int ntiles)
{
    __shared__ float lds[4][16 * 68];
    const int tid  = threadIdx.x;
    const int wid  = tid >> 6;
    const int lane = tid & 63;
    const int c = lane & 15;   // A-row (point) / B-col / D-col
    const int g = lane >> 4;   // k-group
    float* buf = &lds[wid][0];

    // ---- load weight fragments once (held in VGPRs across the tile loop) ----
    bf16x8 w1f[4], w2f[2], winf[4], whf[2][4], woutf[2];
    #pragma unroll
    for (int n4 = 0; n4 < 4; ++n4)
        #pragma unroll
        for (int j = 0; j < 8; ++j)
            w1f[n4][j] = (__bf16)W1[(g * 8 + j) * 64 + n4 * 16 + c];
    #pragma unroll
    for (int kc = 0; kc < 2; ++kc)
        #pragma unroll
        for (int j = 0; j < 8; ++j)
            w2f[kc][j] = (__bf16)W2[(kc * 32 + g * 8 + j) * 16 + c];
    #pragma unroll
    for (int n4 = 0; n4 < 4; ++n4)
        #pragma unroll
        for (int j = 0; j < 8; ++j)
            winf[n4][j] = (__bf16)WIN[(g * 8 + j) * 64 + n4 * 16 + c];
    #pragma unroll
    for (int kc = 0; kc < 2; ++kc)
        #pragma unroll
        for (int n4 = 0; n4 < 4; ++n4)
            #pragma unroll
            for (int j = 0; j < 8; ++j)
                whf[kc][n4][j] = (__bf16)WH[(kc * 32 + g * 8 + j) * 64 + n4 * 16 + c];
    #pragma unroll
    for (int kc = 0; kc < 2; ++kc)
        #pragma unroll
        for (int j = 0; j < 8; ++j)
            woutf[kc][j] = (c < 3) ? (__bf16)WOUT[(kc * 32 + g * 8 + j) * 3 + c]
                                   : (__bf16)0.0f;

    for (int t = blockIdx.x; t < ntiles; t += gridDim.x) {
        const int pbase = t * 64 + wid * 16;
        const int pc = pbase + c;

        // ---- A1 from enc: feats k=8g..8g+7 = levels 4g..4g+3 x {x,y} ----
        bf16x8 a1;
        #pragma unroll
        for (int m = 0; m < 4; ++m) {
            const float2 e = enc[(size_t)(4 * g + m) * n + pc];
            a1[2 * m]     = (__bf16)e.x;
            a1[2 * m + 1] = (__bf16)e.y;
        }

        // ---- layer 1: D1 = A1 @ W1 ; relu -> LDS [16pt][64f] ----
        #pragma unroll
        for (int n4 = 0; n4 < 4; ++n4) {
            f32x4 d = {0.f, 0.f, 0.f, 0.f};
            d = __builtin_amdgcn_mfma_f32_16x16x32_bf16(a1, w1f[n4], d, 0, 0, 0);
            #pragma unroll
            for (int r = 0; r < 4; ++r)
                buf[(g * 4 + r) * 68 + n4 * 16 + c] = fmaxf(d[r], 0.0f);
        }

        // ---- layer 2: h = relu(h1) @ W2 (K=64 -> 2 chunks, N=16) ----
        f32x4 hacc = {0.f, 0.f, 0.f, 0.f};
        #pragma unroll
        for (int kc = 0; kc < 2; ++kc) {
            bf16x8 a2;
            const float* src = &buf[c * 68 + kc * 32 + g * 8];
            #pragma unroll
            for (int j = 0; j < 8; ++j) a2[j] = (__bf16)src[j];
            hacc = __builtin_amdgcn_mfma_f32_16x16x32_bf16(a2, w2f[kc], hacc, 0, 0, 0);
        }

        // sigma = exp(h[:,0])
        if (c == 0) {
            #pragma unroll
            for (int r = 0; r < 4; ++r)
                out[pbase + g * 4 + r] = __expf(hacc[r]);
        }

        // stage raw h into LDS cols 0..15
        #pragma unroll
        for (int r = 0; r < 4; ++r)
            buf[(g * 4 + r) * 68 + c] = hacc[r];

        // ---- SH degree 4 for point pc ----
        const float dx = din[3 * pc + 0];
        const float dy = din[3 * pc + 1];
        const float dz = din[3 * pc + 2];
        const float xy = dx * dy, xz = dx * dz, yz = dy * dz;
        const float x2 = dx * dx, y2 = dy * dy, z2 = dz * dz;
        float shv[16];
        shv[0]  = 0.28209479177387814f;
        shv[1]  = -0.48860251190291987f * dy;
        shv[2]  = 0.48860251190291987f * dz;
        shv[3]  = -0.48860251190291987f * dx;
        shv[4]  = 1.0925484305920792f * xy;
        shv[5]  = -1.0925484305920792f * yz;
        shv[6]  = 0.94617469575756f * z2 - 0.31539156525252f;
        shv[7]  = -1.0925484305920792f * xz;
        shv[8]  = 0.5462742152960396f * (x2 - y2);
        shv[9]  = 0.5900435899266435f * dy * (-3.0f * x2 + y2);
        shv[10] = 2.890611442640554f * xy * dz;
        shv[11] = 0.4570457994644657f * dy * (1.0f - 5.0f * z2);
        shv[12] = 0.3731763325901154f * dz * (5.0f * z2 - 3.0f);
        shv[13] = 0.4570457994644657f * dx * (1.0f - 5.0f * z2);
        shv[14] = 1.445305721320277f * dz * (x2 - y2);
        shv[15] = 0.5900435899266435f * dx * (-x2 + 3.0f * y2);

        // ---- A3 = concat([sh, h]) : k 0..15 sh, 16..31 h ----
        bf16x8 a3;
        if (g < 2) {
            #pragma unroll
            for (int j = 0; j < 8; ++j) a3[j] = (__bf16)shv[g * 8 + j];
        } else {
            const float* hsrc = &buf[c * 68 + (g - 2) * 8];
            #pragma unroll
            for (int j = 0; j < 8; ++j) a3[j] = (__bf16)hsrc[j];
        }

        // ---- layer 3: D3 = A3 @ WIN ; relu -> LDS ----
        #pragma unroll
        for (int n4 = 0; n4 < 4; ++n4) {
            f32x4 d = {0.f, 0.f, 0.f, 0.f};
            d = __builtin_amdgcn_mfma_f32_16x16x32_bf16(a3, winf[n4], d, 0, 0, 0);
            #pragma unroll
            for (int r = 0; r < 4; ++r)
                buf[(g * 4 + r) * 68 + n4 * 16 + c] = fmaxf(d[r], 0.0f);
        }

        // ---- layer 4: D4 = A4 @ WH ; relu -> LDS ----
        bf16x8 a4[2];
        #pragma unroll
        for (int kc = 0; kc < 2; ++kc) {
            const float* src = &buf[c * 68 + kc * 32 + g * 8];
            #pragma unroll
            for (int j = 0; j < 8; ++j) a4[kc][j] = (__bf16)src[j];
        }
        f32x4 d4[4];
        #pragma unroll
        for (int n4 = 0; n4 < 4; ++n4) d4[n4] = (f32x4){0.f, 0.f, 0.f, 0.f};
        #pragma unroll
        for (int kc = 0; kc < 2; ++kc)
            #pragma unroll
            for (int n4 = 0; n4 < 4; ++n4)
                d4[n4] = __builtin_amdgcn_mfma_f32_16x16x32_bf16(a4[kc], whf[kc][n4], d4[n4], 0, 0, 0);
        #pragma unroll
        for (int n4 = 0; n4 < 4; ++n4)
            #pragma unroll
            for (int r = 0; r < 4; ++r)
                buf[(g * 4 + r) * 68 + n4 * 16 + c] = fmaxf(d4[n4][r], 0.0f);

        // ---- layer 5: D5 = A5 @ WOUT(pad16) ; sigmoid ; store rgb ----
        f32x4 d5 = {0.f, 0.f, 0.f, 0.f};
        #pragma unroll
        for (int kc = 0; kc < 2; ++kc) {
            bf16x8 a5;
            const float* src = &buf[c * 68 + kc * 32 + g * 8];
            #pragma unroll
            for (int j = 0; j < 8; ++j) a5[j] = (__bf16)src[j];
            d5 = __builtin_amdgcn_mfma_f32_16x16x32_bf16(a5, woutf[kc], d5, 0, 0, 0);
        }
        if (c < 3) {
            #pragma unroll
            for (int r = 0; r < 4; ++r)
                out[n + 3 * (pbase + g * 4 + r) + c] = 1.0f / (1.0f + __expf(-d5[r]));
        }
    }
}

// ---------------- Fallback scalar MLP ----------------
__global__ void __launch_bounds__(256) ngp_mlp(
    const float2* __restrict__ enc, const float* __restrict__ din,
    const float* __restrict__ W1, const float* __restrict__ W2,
    const float* __restrict__ WIN, const float* __restrict__ WH,
    const float* __restrict__ WOUT, float* __restrict__ out, int n)
{
    const int i = blockIdx.x * 256 + threadIdx.x;
    if (i >= n) return;
    float h1[64];
    #pragma unroll
    for (int j = 0; j < 64; ++j) h1[j] = 0.0f;
    #pragma unroll
    for (int l = 0; l < 16; ++l) {
        const float2 e = enc[(size_t)l * n + i];
        #pragma unroll
        for (int j = 0; j < 64; ++j)
            h1[j] = fmaf(e.x, W1[(2 * l) * 64 + j], fmaf(e.y, W1[(2 * l + 1) * 64 + j], h1[j]));
    }
    float h[16];
    #pragma unroll
    for (int j = 0; j < 16; ++j) h[j] = 0.0f;
    #pragma unroll
    for (int k = 0; k < 64; ++k) {
        const float v = fmaxf(h1[k], 0.0f);
        #pragma unroll
        for (int j = 0; j < 16; ++j) h[j] = fmaf(v, W2[k * 16 + j], h[j]);
    }
    out[i] = __expf(h[0]);
    const float dx = din[3 * i + 0], dy = din[3 * i + 1], dz = din[3 * i + 2];
    const float xy = dx * dy, xz = dx * dz, yz = dy * dz;
    const float x2 = dx * dx, y2 = dy * dy, z2 = dz * dz;
    float sh[16];
    sh[0]  = 0.28209479177387814f;
    sh[1]  = -0.48860251190291987f * dy;
    sh[2]  = 0.48860251190291987f * dz;
    sh[3]  = -0.48860251190291987f * dx;
    sh[4]  = 1.0925484305920792f * xy;
    sh[5]  = -1.0925484305920792f * yz;
    sh[6]  = 0.94617469575756f * z2 - 0.31539156525252f;
    sh[7]  = -1.0925484305920792f * xz;
    sh[8]  = 0.5462742152960396f * (x2 - y2);
    sh[9]  = 0.5900435899266435f * dy * (-3.0f * x2 + y2);
    sh[10] = 2.890611442640554f * xy * dz;
    sh[11] = 0.4570457994644657f * dy * (1.0f - 5.0f * z2);
    sh[12] = 0.3731763325901154f * dz * (5.0f * z2 - 3.0f);
    sh[13] = 0.4570457994644657f * dx * (1.0f - 5.0f * z2);
    sh[14] = 1.445305721320277f * dz * (x2 - y2);
    sh[15] = 0.5900435899266435f * dx * (-x2 + 3.0f * y2);
    float av[64];
    #pragma unroll
    for (int j = 0; j < 64; ++j) av[j] = 0.0f;
    #pragma unroll
    for (int k = 0; k < 16; ++k) {
        const float v = sh[k];
        #pragma unroll
        for (int j = 0; j < 64; ++j) av[j] = fmaf(v, WIN[k * 64 + j], av[j]);
    }
    #pragma unroll
    for (int k = 0; k < 16; ++k) {
        const float v = h[k];
        #pragma unroll
        for (int j = 0; j < 64; ++j) av[j] = fmaf(v, WIN[(16 + k) * 64 + j], av[j]);
    }
    float bv[64];
    #pragma unroll
    for (int j = 0; j < 64; ++j) bv[j] = 0.0f;
    #pragma unroll
    for (int k = 0; k < 64; ++k) {
        const float v = fmaxf(av[k], 0.0f);
        #pragma unroll
        for (int j = 0; j < 64; ++j) bv[j] = fmaf(v, WH[k * 64 + j], bv[j]);
    }
    float r0 = 0.0f, r1 = 0.0f, r2 = 0.0f;
    #pragma unroll
    for (int k = 0; k < 64; ++k) {
        const float v = fmaxf(bv[k], 0.0f);
        r0 = fmaf(v, WOUT[k * 3 + 0], r0);
        r1 = fmaf(v, WOUT[k * 3 + 1], r1);
        r2 = fmaf(v, WOUT[k * 3 + 2], r2);
    }
    out[n + 3 * i + 0] = 1.0f / (1.0f + __expf(-r0));
    out[n + 3 * i + 1] = 1.0f / (1.0f + __expf(-r1));
    out[n + 3 * i + 2] = 1.0f / (1.0f + __expf(-r2));
}

extern "C" void kernel_launch(void* const* d_in, const int* in_sizes, int n_in,
                              void* d_out, int out_size, void* d_ws, size_t ws_size,
                              hipStream_t stream)
{
    const float* x    = (const float*)d_in[0];
    const float* d    = (const float*)d_in[1];
    const float* tb   = (const float*)d_in[2];
    const float* w1   = (const float*)d_in[3];
    const float* w2   = (const float*)d_in[4];
    const float* win  = (const float*)d_in[5];
    const float* wh   = (const float*)d_in[6];
    const float* wout = (const float*)d_in[7];

    const int n = in_sizes[0] / 3;   // 262144
    const size_t enc_bytes = (size_t)16 * n * sizeof(float2);  // 33.5 MB
    float2* enc = (float2*)d_ws;

    // encode: one launch, two XCD-pinned 8-level halves, 2 pts/thread
    const int nblk_half = (n / 512) * 8;   // 4096
    ngp_encode2<<<2 * nblk_half, 256, 0, stream>>>(x, (const float2*)tb, enc, n, nblk_half);

    if (ws_size >= enc_bytes) {
        const int ntiles = n / 64;   // 4096
        ngp_mlp_mfma<<<1024, 256, 0, stream>>>(enc, d, w1, w2, win, wh, wout,
                                               (float*)d_out, n, ntiles);
    } else {
        ngp_mlp<<<n / 256, 256, 0, stream>>>(enc, d, w1, w2, win, wh, wout,
                                             (float*)d_out, n);
    }
}